// Round 1
// baseline (362.192 us; speedup 1.0000x reference)
//
#include <hip/hip_runtime.h>

// Binarized depthwise 3x3 conv, stride 1, SAME, NHWC, sign(0)=+1.
// x: (16,112,112,256) f32, kernel: (3,3,256,1) f32, out: (16,112,112,256) f32.
//
// Round 4: multi-row waves. Each wave computes R=4 output rows x TW=8 columns
// for 4 channels/lane, reading each input row ONCE per wave (6 input rows per
// 4 output rows) instead of 3 rows per output row. Requested read volume drops
// from 3.0x input (~616 MB, served by L3 since input fits in Infinity Cache)
// to ~1.9x (~385 MB), attacking the saturated L3/L2 read path.
//
// Per column cc and channel: rowsig rs = 6 sign bits (input rows h0-1..h0+4,
// bit p = row h0-1+p). For output row r, window = (rs >> r) & 7 vs kernel
// column code kj3[j] (bit i = sign k[i][j]); tap sum = nvalid - 2*popc(xor).
// Border rows drop taps via compile-time masks (tap==0 under SAME zero-pad);
// border columns drop the whole j term (compile-time via tag dispatch).

constexpr int N = 16, H = 112, W = 112, C = 256;
constexpr int TW = 8;   // output columns per wave strip; W/TW = 14
constexpr int R  = 4;   // output rows per wave; 4 waves/block -> 16 rows/block

typedef float f32x4 __attribute__((ext_vector_type(4)));

struct TrueT  { static constexpr bool value = true;  };
struct FalseT { static constexpr bool value = false; };

template<bool TOP, bool BOT>
__device__ __forceinline__ void run_tile(
        const float* __restrict__ x, const float* __restrict__ k,
        float* __restrict__ out, int n, int h0, int w0, int c0) {

    // Kernel sign codes kj3[j][ch]: bit i = sign(k[i][j]) for kernel col j.
    unsigned kj3[3][4] = {{0,0,0,0},{0,0,0,0},{0,0,0,0}};
#pragma unroll
    for (int t = 0; t < 9; ++t) {
        const uint4 kv = *reinterpret_cast<const uint4*>(k + t * C + c0);
        const int kr = t / 3, kj = t % 3;
        kj3[kj][0] |= (kv.x >> 31) << kr;
        kj3[kj][1] |= (kv.y >> 31) << kr;
        kj3[kj][2] |= (kv.z >> 31) << kr;
        kj3[kj][3] |= (kv.w >> 31) << kr;
    }

    constexpr int PLO = TOP ? 1 : 0;      // input rows h0-1+p, p in [PLO,PHI]
    constexpr int PHI = BOT ? R : R + 1;

    const size_t rowstride = (size_t)W * C;
    const float* xin = x + (size_t)(n * H + (h0 - 1)) * rowstride + c0;
    float* o0 = out + (size_t)(n * H + h0) * rowstride + c0;

    // Load one x column: pack sign bits of rows h0-1+p into rs[ch] bit p.
    auto colSig = [&](int cc, unsigned rs[4]) {
        rs[0] = rs[1] = rs[2] = rs[3] = 0u;
        const float* cp = xin + (size_t)cc * C;
#pragma unroll
        for (int p = PLO; p <= PHI; ++p) {
            const uint4 v = *reinterpret_cast<const uint4*>(cp + (size_t)p * rowstride);
            rs[0] |= (v.x >> 31) << p;
            rs[1] |= (v.y >> 31) << p;
            rs[2] |= (v.z >> 31) << p;
            rs[3] |= (v.w >> 31) << p;
        }
    };

    // Emit output column w for all R rows from three columns of rowsig history.
    // rs0 = col w-1 (kernel col 0), rs1 = col w (col 1), rs2 = col w+1 (col 2).
    auto emit = [&](int w, const unsigned rs0[4], const unsigned rs1[4],
                    const unsigned rs2[4], auto h0t, auto h2t) {
#pragma unroll
        for (int r = 0; r < R; ++r) {
            constexpr_if_workaround:;
            const bool border = (TOP && r == 0) || (BOT && r == R - 1);
            const unsigned msk = (TOP && r == 0) ? 0x6u
                               : (BOT && r == R - 1) ? 0x3u : 0x7u;
            const int nr = border ? 2 : 3;
            f32x4 ov;
#pragma unroll
            for (int ch = 0; ch < 4; ++ch) {
                int cnt = 0, nt = 0;
                if constexpr (decltype(h0t)::value) {
                    cnt += __popc(((rs0[ch] >> r) ^ kj3[0][ch]) & msk); nt += nr;
                }
                cnt += __popc(((rs1[ch] >> r) ^ kj3[1][ch]) & msk); nt += nr;
                if constexpr (decltype(h2t)::value) {
                    cnt += __popc(((rs2[ch] >> r) ^ kj3[2][ch]) & msk); nt += nr;
                }
                ov[ch] = (float)(nt - 2 * cnt);
            }
            __builtin_nontemporal_store(ov,
                reinterpret_cast<f32x4*>(o0 + (size_t)r * rowstride + (size_t)w * C));
        }
    };

    unsigned rs_m2[4], rs_m1[4], rs_c[4];

    if (w0 > 0) colSig(w0 - 1, rs_m2);
    else        { rs_m2[0] = rs_m2[1] = rs_m2[2] = rs_m2[3] = 0u; }
    colSig(w0, rs_m1);

    // First output (w = w0) peeled: left-edge strip drops the j=0 term.
    colSig(w0 + 1, rs_c);
    if (w0 > 0) emit(w0, rs_m2, rs_m1, rs_c, TrueT{},  TrueT{});
    else        emit(w0, rs_m2, rs_m1, rs_c, FalseT{}, TrueT{});
#pragma unroll
    for (int ch = 0; ch < 4; ++ch) { rs_m2[ch] = rs_m1[ch]; rs_m1[ch] = rs_c[ch]; }

    // Steady state: all taps present.
#pragma unroll 3
    for (int i = 2; i < TW; ++i) {
        colSig(w0 + i, rs_c);
        emit(w0 + i - 1, rs_m2, rs_m1, rs_c, TrueT{}, TrueT{});
#pragma unroll
        for (int ch = 0; ch < 4; ++ch) { rs_m2[ch] = rs_m1[ch]; rs_m1[ch] = rs_c[ch]; }
    }

    // Last output (w = w0+TW-1): right-edge strip drops the j=2 term.
    if (w0 + TW < W) {
        colSig(w0 + TW, rs_c);
        emit(w0 + TW - 1, rs_m2, rs_m1, rs_c, TrueT{}, TrueT{});
    } else {
        emit(w0 + TW - 1, rs_m2, rs_m1, rs_c, TrueT{}, FalseT{});
    }
}

__global__ __launch_bounds__(256) void bsign_dw3x3_r4(
        const float* __restrict__ x, const float* __restrict__ k,
        float* __restrict__ out) {
    const int c0 = (threadIdx.x & 63) << 2;   // 4 channels per lane
    const int wq = threadIdx.x >> 6;          // wave -> row group within block
    const int h0 = blockIdx.y * (4 * R) + wq * R;
    const int w0 = blockIdx.x * TW;
    const int n  = blockIdx.z;

    if (h0 == 0)           run_tile<true,  false>(x, k, out, n, h0, w0, c0);
    else if (h0 == H - R)  run_tile<false, true >(x, k, out, n, h0, w0, c0);
    else                   run_tile<false, false>(x, k, out, n, h0, w0, c0);
}

extern "C" void kernel_launch(void* const* d_in, const int* in_sizes, int n_in,
                              void* d_out, int out_size, void* d_ws, size_t ws_size,
                              hipStream_t stream) {
    const float* x = (const float*)d_in[0];   // (16,112,112,256) f32
    const float* k = (const float*)d_in[1];   // (3,3,256,1) f32
    float* out = (float*)d_out;               // (16,112,112,256) f32

    dim3 grid(W / TW, H / (4 * R), N);        // (14, 7, 16)
    bsign_dw3x3_r4<<<grid, 256, 0, stream>>>(x, k, out);
}

// Round 2
// 345.165 us; speedup vs baseline: 1.0493x; 1.0493x over previous
//
#include <hip/hip_runtime.h>

// Binarized depthwise 3x3 conv, stride 1, SAME, NHWC, sign(0)=+1.
// x: (16,112,112,256) f32, kernel: (3,3,256,1) f32, out: (16,112,112,256) f32.
//
// Round 5: R=4 multi-row waves (each input row read once per wave; requested
// read volume 1.875x input vs 3.0x for single-row) + 2 channels/lane packed
// into a single sign-bit register to stay under the 64-VGPR occupancy cliff
// (round-4's 68 VGPR -> 4 waves/SIMD was the regression cause) and double the
// wave count (6272 -> 12544, 12.25 waves/SIMD demanded, 8 resident).
//
// Packing: rowsig rs holds ch0 sign bits at [0..5], ch1 at [16..21]
// (bit p = input row h0-1+p). Kernel col code kj3[j]: ch0 bits [0..2],
// ch1 bits [16..18]. For output row r: x = (rs >> r) ^ kj3[j];
// cnt_ch0 = popc(x & msk), cnt_ch1 = popc(x & (msk<<16)); tap sum =
// nvalid - 2*cnt. Border rows shrink msk at compile time; border columns
// drop the whole j term (tag dispatch). Zero-padding contributes nothing
// because padding is applied AFTER quantization in the reference.

constexpr int N = 16, H = 112, W = 112, C = 256;
constexpr int TW = 8;   // output columns per wave strip; W/TW = 14
constexpr int R  = 4;   // output rows per wave; 4 waves/block -> 16 rows/block

typedef float f32x2 __attribute__((ext_vector_type(2)));

struct TrueT  { static constexpr bool value = true;  };
struct FalseT { static constexpr bool value = false; };

template<bool TOP, bool BOT>
__device__ __forceinline__ void run_tile(
        const float* __restrict__ x, const float* __restrict__ k,
        float* __restrict__ out, int n, int h0, int w0, int c0) {

    // Kernel sign codes, both channels packed: kj3[j] bit kr (ch0), 16+kr (ch1).
    unsigned kj3[3] = {0u, 0u, 0u};
#pragma unroll
    for (int t = 0; t < 9; ++t) {
        const uint2 kv = *reinterpret_cast<const uint2*>(k + t * C + c0);
        const int kr = t / 3, kj = t % 3;
        kj3[kj] |= ((kv.x >> 31) << kr) | ((kv.y >> 31) << (16 + kr));
    }

    constexpr int PLO = TOP ? 1 : 0;      // input rows h0-1+p, p in [PLO,PHI]
    constexpr int PHI = BOT ? R : R + 1;

    const size_t rowstride = (size_t)W * C;
    const float* xin = x + (size_t)(n * H + (h0 - 1)) * rowstride + c0;
    float* o0 = out + (size_t)(n * H + h0) * rowstride + c0;

    // Load one x column: pack sign bits of rows h0-1+p into bits p (ch0)
    // and 16+p (ch1) of one register. 6 independent 8B loads, 512B/wave each.
    auto colSig = [&](int cc) -> unsigned {
        unsigned rs = 0u;
        const float* cp = xin + (size_t)cc * C;
#pragma unroll
        for (int p = PLO; p <= PHI; ++p) {
            const uint2 v = *reinterpret_cast<const uint2*>(cp + (size_t)p * rowstride);
            rs |= ((v.x >> 31) << p) | ((v.y >> 31) << (16 + p));
        }
        return rs;
    };

    // Emit output column w for all R rows. rs0 = col w-1 (kernel col 0),
    // rs1 = col w (col 1), rs2 = col w+1 (col 2). jt0/jt2 drop edge terms.
    auto emit = [&](int w, unsigned rs0, unsigned rs1, unsigned rs2,
                    auto jt0, auto jt2) {
#pragma unroll
        for (int r = 0; r < R; ++r) {
            const bool border = (TOP && r == 0) || (BOT && r == R - 1);
            const unsigned m0 = (TOP && r == 0) ? 0x6u
                              : (BOT && r == R - 1) ? 0x3u : 0x7u;
            const unsigned m1 = m0 << 16;
            const int nr = border ? 2 : 3;
            int cnt0 = 0, cnt1 = 0, nt = 0;
            if constexpr (decltype(jt0)::value) {
                const unsigned xx = (rs0 >> r) ^ kj3[0];
                cnt0 += __popc(xx & m0); cnt1 += __popc(xx & m1); nt += nr;
            }
            {
                const unsigned xx = (rs1 >> r) ^ kj3[1];
                cnt0 += __popc(xx & m0); cnt1 += __popc(xx & m1); nt += nr;
            }
            if constexpr (decltype(jt2)::value) {
                const unsigned xx = (rs2 >> r) ^ kj3[2];
                cnt0 += __popc(xx & m0); cnt1 += __popc(xx & m1); nt += nr;
            }
            f32x2 ov;
            ov[0] = (float)(nt - 2 * cnt0);
            ov[1] = (float)(nt - 2 * cnt1);
            __builtin_nontemporal_store(ov,
                reinterpret_cast<f32x2*>(o0 + (size_t)r * rowstride + (size_t)w * C));
        }
    };

    unsigned rs_m2, rs_m1, rs_c;

    rs_m2 = (w0 > 0) ? colSig(w0 - 1) : 0u;
    rs_m1 = colSig(w0);

    // First output (w = w0): left-edge strip drops the j=0 term.
    rs_c = colSig(w0 + 1);
    if (w0 > 0) emit(w0, rs_m2, rs_m1, rs_c, TrueT{},  TrueT{});
    else        emit(w0, rs_m2, rs_m1, rs_c, FalseT{}, TrueT{});
    rs_m2 = rs_m1; rs_m1 = rs_c;

    // Steady state: all taps present.
#pragma unroll 3
    for (int i = 2; i < TW; ++i) {
        rs_c = colSig(w0 + i);
        emit(w0 + i - 1, rs_m2, rs_m1, rs_c, TrueT{}, TrueT{});
        rs_m2 = rs_m1; rs_m1 = rs_c;
    }

    // Last output (w = w0+TW-1): right-edge strip drops the j=2 term.
    if (w0 + TW < W) {
        rs_c = colSig(w0 + TW);
        emit(w0 + TW - 1, rs_m2, rs_m1, rs_c, TrueT{}, TrueT{});
    } else {
        emit(w0 + TW - 1, rs_m2, rs_m1, rs_c, TrueT{}, FalseT{});
    }
}

__global__ __launch_bounds__(256) void bsign_dw3x3_r4c2(
        const float* __restrict__ x, const float* __restrict__ k,
        float* __restrict__ out) {
    const int lane = threadIdx.x & 63;
    const int wq   = threadIdx.x >> 6;          // wave -> row group within block
    const int ch   = blockIdx.z & 1;            // channel half
    const int n    = blockIdx.z >> 1;
    const int c0   = (lane << 1) + (ch << 7);   // 2 channels per lane
    const int h0   = blockIdx.y * (4 * R) + wq * R;
    const int w0   = blockIdx.x * TW;

    if (h0 == 0)           run_tile<true,  false>(x, k, out, n, h0, w0, c0);
    else if (h0 == H - R)  run_tile<false, true >(x, k, out, n, h0, w0, c0);
    else                   run_tile<false, false>(x, k, out, n, h0, w0, c0);
}

extern "C" void kernel_launch(void* const* d_in, const int* in_sizes, int n_in,
                              void* d_out, int out_size, void* d_ws, size_t ws_size,
                              hipStream_t stream) {
    const float* x = (const float*)d_in[0];   // (16,112,112,256) f32
    const float* k = (const float*)d_in[1];   // (3,3,256,1) f32
    float* out = (float*)d_out;               // (16,112,112,256) f32

    dim3 grid(W / TW, H / (4 * R), N * 2);    // (14, 7, 32)
    bsign_dw3x3_r4c2<<<grid, 256, 0, stream>>>(x, k, out);
}